// Round 3
// baseline (1406.570 us; speedup 1.0000x reference)
//
#include <hip/hip_runtime.h>
#include <math.h>

#define TT 1024
#define U1 128
#define U2 32
#define NCOL 480   // 384 rk1 gate-cols + 96 k2 cols (both dot against h1)
#define NQ 120     // long-col quads per u-quarter
#define NUQ 4      // u-quarters

__device__ __forceinline__ float fast_tanh(float v) {
    float e = __expf(2.f * v);      // v>>0: e=inf -> 1; v<<0: e=0 -> -1 (NaN-free)
    return 1.f - 2.f / (e + 1.f);
}
__device__ __forceinline__ float fast_sig(float v) {
    return 1.f / (1.f + __expf(-v));
}

// 256 blocks x 512 threads; block owns batches {2b, 2b+1}, SOFTWARE-PIPELINED
// half a step apart so each barrier interval contains one batch's dot AND the
// other batch's update (no dedicated update phase, 1 barrier/phase).
//   phase p: X=p&1 is dotted at step i_dot=p>>1 (reads h_X, writes part_X);
//            Y=1-X is updated at step i_u=(p-1)>>1 (reads part_Y from phase
//            p-1 — stable since last barrier, so its LDS reads issue at phase
//            start and the latency hides under the dot FMAs).
// Dot roles (same mapping as the proven 104-VGPR kernel): t<480 owns 4 cols x
//   32-u of [rk1|k2] vs h1; t 480..503 rk2 vs h2. Weights are column-owned,
//   batch-independent: one w4[32] serves both batches.
// Update roles on waves 5-7: t 320..447 GRU1 unit ju=t-320 (keeps h_old for
//   BOTH batches in regs); t 448..479 GRU2 unit j2=t-448.
// x rows staged to LDS once (xs[2][1024]) - no global loads in the loop.
__global__ __launch_bounds__(512, 1)
void gru_stack_kernel(const float* __restrict__ x,   // [512,1024,1]
                      const float* __restrict__ k1,  // [1,384]
                      const float* __restrict__ rk1, // [128,384]
                      const float* __restrict__ b1,  // [2,384]
                      const float* __restrict__ k2,  // [128,96]
                      const float* __restrict__ rk2, // [32,96]
                      const float* __restrict__ b2,  // [2,96]
                      const float* __restrict__ wd,  // [32,1]
                      const float* __restrict__ bd,  // [1]
                      float* __restrict__ out)       // [512,1]
{
    __shared__ __align__(16) float h1s[2][U1];
    __shared__ __align__(16) float h2s[2][U2];
    __shared__ __align__(16) float part1[2][NUQ][NCOL];  // [batch][uq][col]
    __shared__ __align__(16) float part2[2][96];         // rk2 partials
    __shared__ __align__(16) float xs[2][TT];            // staged x rows

    const int t  = threadIdx.x;
    const int b0 = blockIdx.x * 2;

    if (t < 2 * U1) ((float*)h1s)[t] = 0.f;
    if (t < 2 * U2) ((float*)h2s)[t] = 0.f;
    for (int idx = t; idx < 2 * TT; idx += 512)          // coalesced x stage
        ((float*)xs)[idx] = x[b0 * TT + idx];

    // ---------------- dot-role setup ----------------
    float4 w4[32];                      // weights for 4 cols x 32 u
    const float4* pb0 = nullptr;        // h source, batch 0
    const float4* pb1 = nullptr;        // h source, batch 1
    float4* pd0 = nullptr;              // partial dest, batch 0
    float4* pd1 = nullptr;
    const bool is_dot = (t < 504);
    if (t < 480) {
        const int uq = t / NQ, q = t % NQ;
        const int c0 = 4 * q, ub = 32 * uq;
#pragma unroll
        for (int j = 0; j < 32; ++j) {
            const int u = ub + j;
            float vv[4];
#pragma unroll
            for (int r = 0; r < 4; ++r) {
                const int c = c0 + r;
                vv[r] = (c < 384) ? rk1[u * 384 + c] : k2[u * 96 + (c - 384)];
            }
            w4[j] = make_float4(vv[0], vv[1], vv[2], vv[3]);
        }
        pb0 = (const float4*)&h1s[0][ub];
        pb1 = (const float4*)&h1s[1][ub];
        pd0 = (float4*)&part1[0][uq][c0];
        pd1 = (float4*)&part1[1][uq][c0];
    } else if (t < 504) {
        const int q2 = t - 480, c0 = 4 * q2;
#pragma unroll
        for (int j = 0; j < 32; ++j)
            w4[j] = make_float4(rk2[j * 96 + c0 + 0], rk2[j * 96 + c0 + 1],
                                rk2[j * 96 + c0 + 2], rk2[j * 96 + c0 + 3]);
        pb0 = (const float4*)&h2s[0][0];
        pb1 = (const float4*)&h2s[1][0];
        pd0 = (float4*)&part2[0][c0];
        pd1 = (float4*)&part2[1][c0];
    }

    // ---------------- update-role setup ----------------
    const int ju = t - 320;                            // t 320..447: GRU1 update
    const bool isU1 = (t >= 320 && t < 448);
    float k1z = 0, k1r = 0, k1h = 0, bz = 0, br = 0, bhx = 0, bhr = 0;
    float hoA = 0.f, hoB = 0.f;                        // h_old per batch
    if (isU1) {
        k1z = k1[ju]; k1r = k1[128 + ju]; k1h = k1[256 + ju];
        bz  = b1[ju]       + b1[384 + ju];
        br  = b1[128 + ju] + b1[384 + 128 + ju];
        bhx = b1[256 + ju];
        bhr = b1[384 + 256 + ju];
    }
    const int j2 = t - 448;                            // t 448..479: GRU2 update
    const bool isU2 = (t >= 448 && t < 480);
    float bz2 = 0, br2 = 0, bh2x = 0, bh2r = 0;
    float h2oA = 0.f, h2oB = 0.f;
    if (isU2) {
        bz2  = b2[j2]      + b2[96 + j2];
        br2  = b2[32 + j2] + b2[96 + 32 + j2];
        bh2x = b2[64 + j2];
        bh2r = b2[96 + 64 + j2];
    }

    __syncthreads();  // h init + x stage visible

    // 2*TT+3 phases: dot X=p&1 at i_dot=p>>1 (while i_dot<=TT);
    // update Y=1-X at i_u=(p-1)>>1 (GRU1 while i_u<TT, GRU2 while 1<=i_u<=TT).
    for (int p = 0; p <= 2 * TT + 2; ++p) {
        const int X = p & 1, Y = 1 - X;
        const int i_dot = p >> 1;
        const int i_u   = (p - 1) >> 1;
        const bool doU1 = isU1 && (p >= 1) && (i_u < TT);
        const bool doU2 = isU2 && (i_u >= 1);          // p>=3 implied; i_u<=TT by loop bound

        // ---- early reads for the update (data stable since last barrier) ----
        float e_xv = 0, e_iz = 0, e_ir = 0, e_ih = 0;
        if (doU1) {
            e_xv = xs[Y][i_u];
            e_iz = part1[Y][0][ju] + part1[Y][1][ju]
                 + part1[Y][2][ju] + part1[Y][3][ju];
            e_ir = part1[Y][0][128 + ju] + part1[Y][1][128 + ju]
                 + part1[Y][2][128 + ju] + part1[Y][3][128 + ju];
            e_ih = part1[Y][0][256 + ju] + part1[Y][1][256 + ju]
                 + part1[Y][2][256 + ju] + part1[Y][3][256 + ju];
        }
        float g_xz = 0, g_xr = 0, g_xh = 0, g_iz = 0, g_ir = 0, g_ih = 0;
        if (doU2) {
            g_xz = part1[Y][0][384 + j2] + part1[Y][1][384 + j2]
                 + part1[Y][2][384 + j2] + part1[Y][3][384 + j2];
            g_xr = part1[Y][0][416 + j2] + part1[Y][1][416 + j2]
                 + part1[Y][2][416 + j2] + part1[Y][3][416 + j2];
            g_xh = part1[Y][0][448 + j2] + part1[Y][1][448 + j2]
                 + part1[Y][2][448 + j2] + part1[Y][3][448 + j2];
            g_iz = part2[Y][j2];
            g_ir = part2[Y][32 + j2];
            g_ih = part2[Y][64 + j2];
        }

        // ---- dot: batch X at step i_dot ----
        if (is_dot && i_dot <= TT) {
            const float4* pb = X ? pb1 : pb0;
            float4 a = make_float4(0.f, 0.f, 0.f, 0.f);
#pragma unroll
            for (int j4 = 0; j4 < 8; ++j4) {
                float4 hv = pb[j4];
                float ha[4] = {hv.x, hv.y, hv.z, hv.w};
#pragma unroll
                for (int e = 0; e < 4; ++e) {
                    const float4 wv = w4[4 * j4 + e];
                    const float he = ha[e];
                    a.x = fmaf(he, wv.x, a.x);
                    a.y = fmaf(he, wv.y, a.y);
                    a.z = fmaf(he, wv.z, a.z);
                    a.w = fmaf(he, wv.w, a.w);
                }
            }
            *(X ? pd1 : pd0) = a;
        }

        // ---- finish update: batch Y ----
        if (doU1) {
            // GRU1: z/r = relu, hh = tanh (reset_after)
            float z  = fmaxf(fmaf(e_xv, k1z, bz) + e_iz, 0.f);
            float r  = fmaxf(fmaf(e_xv, k1r, br) + e_ir, 0.f);
            float hh = fast_tanh(fmaf(e_xv, k1h, bhx) + r * (e_ih + bhr));
            float ho = Y ? hoB : hoA;
            float hn = fmaf(z, ho - hh, hh);
            if (Y) hoB = hn; else hoA = hn;
            h1s[Y][ju] = hn;
        }
        if (doU2) {
            // GRU2: z/r = sigmoid, hh = relu (one step behind GRU1)
            float z  = fast_sig(g_xz + g_iz + bz2);
            float r  = fast_sig(g_xr + g_ir + br2);
            float hh = fmaxf(g_xh + bh2x + r * (g_ih + bh2r), 0.f);
            float ho = Y ? h2oB : h2oA;
            float hn = fmaf(z, ho - hh, hh);
            if (Y) h2oB = hn; else h2oA = hn;
            h2s[Y][j2] = hn;
        }
        __syncthreads();
    }

    // ---------------- dense head ----------------
    if (t < 64) {
        const int b = t >> 5, j = t & 31;
        float p = h2s[b][j] * wd[j];
#pragma unroll
        for (int m = 16; m >= 1; m >>= 1) p += __shfl_xor(p, m, 64);
        if (j == 0) out[b0 + b] = p + bd[0];
    }
}

extern "C" void kernel_launch(void* const* d_in, const int* in_sizes, int n_in,
                              void* d_out, int out_size, void* d_ws, size_t ws_size,
                              hipStream_t stream) {
    const float* x   = (const float*)d_in[0];
    const float* k1  = (const float*)d_in[1];
    const float* rk1 = (const float*)d_in[2];
    const float* b1  = (const float*)d_in[3];
    const float* k2  = (const float*)d_in[4];
    const float* rk2 = (const float*)d_in[5];
    const float* b2  = (const float*)d_in[6];
    const float* wd  = (const float*)d_in[7];
    const float* bd  = (const float*)d_in[8];
    float* out = (float*)d_out;

    dim3 grid(256), block(512);
    hipLaunchKernelGGL(gru_stack_kernel, grid, block, 0, stream,
                       x, k1, rk1, b1, k2, rk2, b2, wd, bd, out);
}